// Round 12
// baseline (238.742 us; speedup 1.0000x reference)
//
#include <hip/hip_runtime.h>
#include <cstddef>

#define N_NODES 65536
#define NPER    1024
#define NGRAPH  64
#define HID     64
#define IN_F    128
#define KCLUS   16
#define NCLS    10
#define ECAP    20480   // per-graph capacity incl. 4-alignment padding
#define HSTRIDE 12      // node-major LDS row stride (48 B, 16B-aligned)
#define ZROW    NPER    // index of the all-zero LDS row used by padding entries

// ---------------------------------------------------------------- bucket edges by graph
__global__ __launch_bounds__(256) void bucket_kernel(const int* __restrict__ src,
                                                     const int* __restrict__ dst,
                                                     int* __restrict__ ecnt,
                                                     int* __restrict__ gedges, int E) {
    __shared__ int hist[NGRAPH];
    __shared__ int base_l[NGRAPH];
    const int t = threadIdx.x;
    const int e0 = blockIdx.x * 1024;
    if (t < NGRAPH) hist[t] = 0;
    __syncthreads();

    int gg[4], rr[4], pk[4];
#pragma unroll
    for (int i = 0; i < 4; ++i) {
        int idx = e0 + i * 256 + t;
        if (idx < E) {
            int d = dst[idx], s = src[idx];
            int g = d >> 10;
            gg[i] = g;
            pk[i] = ((d & 1023) << 10) | (s & 1023);
            rr[i] = atomicAdd(&hist[g], 1);
        } else gg[i] = -1;
    }
    __syncthreads();
    if (t < NGRAPH) base_l[t] = atomicAdd(&ecnt[t], hist[t]);
    __syncthreads();
#pragma unroll
    for (int i = 0; i < 4; ++i) {
        if (gg[i] >= 0) {
            int pos = base_l[gg[i]] + rr[i];
            if (pos < ECAP) gedges[gg[i] * ECAP + pos] = pk[i];
        }
    }
}

// ---------------------------------------------------------------- per-graph CSR build in LDS (shuffle-scan)
// Ranges padded to multiples of 4; padding entries -> ZROW (zero row).
__global__ __launch_bounds__(1024) void csr_kernel(const int* __restrict__ gedges,
                                                   const int* __restrict__ ecnt,
                                                   int* __restrict__ rp,
                                                   unsigned short* __restrict__ esorted,
                                                   float* __restrict__ dinv) {
    __shared__ int hist[NPER];
    __shared__ int wsum[16];
    const int g = blockIdx.x, t = threadIdx.x;
    const int lane = t & 63, wid = t >> 6;
    const int ec = ecnt[g];
    const int* ge = gedges + (size_t)g * ECAP;

    hist[t] = 0;
    __syncthreads();
    for (int i = t; i < ec; i += 1024) atomicAdd(&hist[ge[i] >> 10], 1);
    __syncthreads();

    const int h0 = hist[t];
    const int pd = (h0 + 3) & ~3;   // padded degree
    int v = pd;
#pragma unroll
    for (int off = 1; off < 64; off <<= 1) {
        int x = __shfl_up(v, off, 64);
        if (lane >= off) v += x;
    }
    if (lane == 63) wsum[wid] = v;
    __syncthreads();
    if (wid == 0) {
        int wv = (lane < 16) ? wsum[lane] : 0;
#pragma unroll
        for (int off = 1; off < 16; off <<= 1) {
            int x = __shfl_up(wv, off, 64);
            if (lane >= off) wv += x;
        }
        if (lane < 16) wsum[lane] = wv;
    }
    __syncthreads();
    const int incl = v + (wid > 0 ? wsum[wid - 1] : 0);
    const int excl = incl - pd;

    rp[g * (NPER + 1) + t] = excl;
    if (t == NPER - 1) rp[g * (NPER + 1) + NPER] = incl;
    dinv[g * NPER + t] = rsqrtf((float)h0 + 1.0f);   // exact degree

    hist[t] = excl;   // scatter cursor
    __syncthreads();

    unsigned short* es = esorted + (size_t)g * ECAP;
    for (int i = t; i < ec; i += 1024) {
        int pk = ge[i];
        int pos = atomicAdd(&hist[pk >> 10], 1);
        es[pos] = (unsigned short)(pk & 1023);
    }
    __syncthreads();
    for (int q = excl + h0; q < excl + pd; ++q) es[q] = (unsigned short)ZROW;
}

// ---------------------------------------------------------------- fused GCN conv: (X @ W^T slice) -> LDS -> pull-agg -> relu
// Block (g, fq): computes A[g-nodes][f0:f0+8] itself (VALU-bound GEMM vs LDS wsl),
// then aggregates over edges. XCD-swizzled so the 8 slice-blocks of a graph
// share one XCD's L2 for the X rows (and conv2's X = prior output, L2-warm).
template <int K>
__global__ __launch_bounds__(512) void conv_kernel(const float* __restrict__ X,
                                                   const float* __restrict__ W,
                                                   const float* __restrict__ bias,
                                                   const unsigned short* __restrict__ esorted,
                                                   const int* __restrict__ rp,
                                                   const float* __restrict__ dinv,
                                                   float* __restrict__ outp) {
    __shared__ float Hs[(NPER + 1) * HSTRIDE];
    __shared__ float dl[NPER];
    __shared__ float wsl[K][8];          // W slice, K-major, 32B rows
    const int g = blockIdx.x & 63;       // same-XCD grouping (%8 invariant)
    const int f0 = (blockIdx.x >> 6) * 8;
    const int t = threadIdx.x;
    const int base = g * NPER;

    for (int i = t; i < K * 8; i += 512) {
        int c = i & 7, k = i >> 3;
        wsl[k][c] = W[(f0 + c) * K + k];
    }
    if (t < HSTRIDE) Hs[ZROW * HSTRIDE + t] = 0.f;
    float bb[8];
#pragma unroll
    for (int j = 0; j < 8; ++j) bb[j] = bias[f0 + j];
    __syncthreads();

    // GEMM phase: rows t and t+512
    {
        float acc0[8] = {}, acc1[8] = {};
        const float* x0 = X + (size_t)(base + t) * K;
        const float* x1 = X + (size_t)(base + t + 512) * K;
        for (int k4 = 0; k4 < K; k4 += 4) {
            float4 xa = *(const float4*)(x0 + k4);
            float4 xb = *(const float4*)(x1 + k4);
#pragma unroll
            for (int kk = 0; kk < 4; ++kk) {
                float xs0 = (kk == 0) ? xa.x : (kk == 1) ? xa.y : (kk == 2) ? xa.z : xa.w;
                float xs1 = (kk == 0) ? xb.x : (kk == 1) ? xb.y : (kk == 2) ? xb.z : xb.w;
                const float* wr = wsl[k4 + kk];
#pragma unroll
                for (int c = 0; c < 8; ++c) {
                    float wv = wr[c];
                    acc0[c] = fmaf(xs0, wv, acc0[c]);
                    acc1[c] = fmaf(xs1, wv, acc1[c]);
                }
            }
        }
        float dv0 = dinv[base + t];
        float dv1 = dinv[base + t + 512];
        dl[t] = dv0;
        dl[t + 512] = dv1;
        float* r0 = &Hs[t * HSTRIDE];
        float* r1 = &Hs[(t + 512) * HSTRIDE];
        *(float4*)r0       = make_float4(acc0[0] * dv0, acc0[1] * dv0, acc0[2] * dv0, acc0[3] * dv0);
        *(float4*)(r0 + 4) = make_float4(acc0[4] * dv0, acc0[5] * dv0, acc0[6] * dv0, acc0[7] * dv0);
        *(float4*)r1       = make_float4(acc1[0] * dv1, acc1[1] * dv1, acc1[2] * dv1, acc1[3] * dv1);
        *(float4*)(r1 + 4) = make_float4(acc1[4] * dv1, acc1[5] * dv1, acc1[6] * dv1, acc1[7] * dv1);
    }
    const unsigned short* es = esorted + (size_t)g * ECAP;
    const int* rpg = rp + g * (NPER + 1);
    __syncthreads();

    // aggregation phase (padded CSR: aligned uint2 per 4 edges, zero-row padding)
    for (int ld = t; ld < NPER; ld += 512) {
        int p = rpg[ld];
        const int pe = rpg[ld + 1];
        const float* srow = &Hs[ld * HSTRIDE];
        float4 acc0 = *(const float4*)srow;  // self-loop term
        float4 acc1 = *(const float4*)(srow + 4);
        float4 bcc0 = make_float4(0.f, 0.f, 0.f, 0.f);
        float4 bcc1 = make_float4(0.f, 0.f, 0.f, 0.f);

        for (; p < pe; p += 4) {
            uint2 w4 = *(const uint2*)(es + p);
            const float* r0 = &Hs[(int)(w4.x & 0xFFFFu) * HSTRIDE];
            const float* r1 = &Hs[(int)(w4.x >> 16) * HSTRIDE];
            const float* r2 = &Hs[(int)(w4.y & 0xFFFFu) * HSTRIDE];
            const float* r3 = &Hs[(int)(w4.y >> 16) * HSTRIDE];
            float4 a0 = *(const float4*)r0, a1 = *(const float4*)(r0 + 4);
            float4 b0 = *(const float4*)r1, b1 = *(const float4*)(r1 + 4);
            float4 c0v = *(const float4*)r2, c1v = *(const float4*)(r2 + 4);
            float4 d0 = *(const float4*)r3, d1 = *(const float4*)(r3 + 4);
            acc0.x += a0.x; acc0.y += a0.y; acc0.z += a0.z; acc0.w += a0.w;
            acc1.x += a1.x; acc1.y += a1.y; acc1.z += a1.z; acc1.w += a1.w;
            bcc0.x += b0.x; bcc0.y += b0.y; bcc0.z += b0.z; bcc0.w += b0.w;
            bcc1.x += b1.x; bcc1.y += b1.y; bcc1.z += b1.z; bcc1.w += b1.w;
            acc0.x += c0v.x; acc0.y += c0v.y; acc0.z += c0v.z; acc0.w += c0v.w;
            acc1.x += c1v.x; acc1.y += c1v.y; acc1.z += c1v.z; acc1.w += c1v.w;
            bcc0.x += d0.x; bcc0.y += d0.y; bcc0.z += d0.z; bcc0.w += d0.w;
            bcc1.x += d1.x; bcc1.y += d1.y; bcc1.z += d1.z; bcc1.w += d1.w;
        }
        acc0.x += bcc0.x; acc0.y += bcc0.y; acc0.z += bcc0.z; acc0.w += bcc0.w;
        acc1.x += bcc1.x; acc1.y += bcc1.y; acc1.z += bcc1.z; acc1.w += bcc1.w;

        const float dv = dl[ld];
        float4 o0, o1;
        o0.x = fmaxf(fmaf(acc0.x, dv, bb[0]), 0.f);
        o0.y = fmaxf(fmaf(acc0.y, dv, bb[1]), 0.f);
        o0.z = fmaxf(fmaf(acc0.z, dv, bb[2]), 0.f);
        o0.w = fmaxf(fmaf(acc0.w, dv, bb[3]), 0.f);
        o1.x = fmaxf(fmaf(acc1.x, dv, bb[4]), 0.f);
        o1.y = fmaxf(fmaf(acc1.y, dv, bb[5]), 0.f);
        o1.z = fmaxf(fmaf(acc1.z, dv, bb[6]), 0.f);
        o1.w = fmaxf(fmaf(acc1.w, dv, bb[7]), 0.f);
        float* op = outp + (size_t)(base + ld) * HID + f0;
        *(float4*)op = o0;
        *(float4*)(op + 4) = o1;
    }
}

// ---------------------------------------------------------------- fused DMoN phase 1: softmax assignment + partial cluster sums
__global__ __launch_bounds__(256) void pool1_kernel(const float* __restrict__ h,
                                                    const float* __restrict__ Wp,
                                                    const float* __restrict__ bp,
                                                    float* __restrict__ xpart) {
    __shared__ float xs[128][HID + 1];
    __shared__ float ss[128][KCLUS + 1];
    __shared__ float wp[KCLUS][HID];
    __shared__ float bps[KCLUS];
    const int g = blockIdx.x >> 3;
    const int c = blockIdx.x & 7;
    const int t = threadIdx.x;
    const float* hb = h + ((size_t)g * NPER + c * 128) * HID;

    for (int i = t; i < 128 * HID / 4; i += 256) {
        float4 v = ((const float4*)hb)[i];
        int row = i >> 4, col = (i & 15) * 4;
        xs[row][col] = v.x; xs[row][col + 1] = v.y; xs[row][col + 2] = v.z; xs[row][col + 3] = v.w;
    }
    for (int i = t; i < KCLUS * HID; i += 256) wp[i >> 6][i & 63] = Wp[i];
    if (t < KCLUS) bps[t] = bp[t];
    __syncthreads();

    if (t < 128) {
        float lg[KCLUS];
        float mx = -1e30f;
#pragma unroll
        for (int k = 0; k < KCLUS; ++k) {
            float a = bps[k];
#pragma unroll 8
            for (int hh = 0; hh < HID; ++hh) a = fmaf(xs[t][hh], wp[k][hh], a);
            lg[k] = a;
            mx = fmaxf(mx, a);
        }
        float sum = 0.f;
#pragma unroll
        for (int k = 0; k < KCLUS; ++k) {
            lg[k] = __expf(lg[k] - mx);
            sum += lg[k];
        }
        float inv = 1.0f / sum;
#pragma unroll
        for (int k = 0; k < KCLUS; ++k) ss[t][k] = lg[k] * inv;
    }
    __syncthreads();

    const int hcol = t & 63;
    const int k0 = (t >> 6) * 4;
    float a0 = 0.f, a1 = 0.f, a2 = 0.f, a3 = 0.f;
#pragma unroll 8
    for (int n = 0; n < 128; ++n) {
        float xv = xs[n][hcol];
        a0 = fmaf(ss[n][k0 + 0], xv, a0);
        a1 = fmaf(ss[n][k0 + 1], xv, a1);
        a2 = fmaf(ss[n][k0 + 2], xv, a2);
        a3 = fmaf(ss[n][k0 + 3], xv, a3);
    }
    float* xp = xpart + (((size_t)(g * 8 + c)) * KCLUS + k0) * HID + hcol;
    xp[0] = a0; xp[HID] = a1; xp[2 * HID] = a2; xp[3 * HID] = a3;
}

// ---------------------------------------------------------------- DMoN phase 2: reduce partials, selu, mean, classifier
__global__ __launch_bounds__(256) void pool2_kernel(const float* __restrict__ xpart,
                                                    const float* __restrict__ Wl,
                                                    const float* __restrict__ bl,
                                                    float* __restrict__ out) {
    __shared__ float xp[KCLUS][HID + 1];
    __shared__ float outm[HID];
    const int g = blockIdx.x;
    const int t = threadIdx.x;
    const int hcol = t & 63;
    const int k0 = (t >> 6) * 4;
    const float* base = xpart + (size_t)g * 8 * KCLUS * HID;

    float a[4] = {};
#pragma unroll
    for (int c = 0; c < 8; ++c)
#pragma unroll
        for (int j = 0; j < 4; ++j)
            a[j] += base[(c * KCLUS + k0 + j) * HID + hcol];

    const float sc = 1.0507009873554805f, al = 1.6732632423543772f;
#pragma unroll
    for (int j = 0; j < 4; ++j) {
        float v = a[j];
        xp[k0 + j][hcol] = v > 0.f ? sc * v : sc * al * (__expf(v) - 1.f);
    }
    __syncthreads();

    if (t < HID) {
        float m = 0.f;
#pragma unroll
        for (int k = 0; k < KCLUS; ++k) m += xp[k][t];
        outm[t] = m * (1.0f / KCLUS);
    }
    __syncthreads();

    if (t < NCLS) {
        float acc = bl[t];
#pragma unroll 8
        for (int hh = 0; hh < HID; ++hh) acc = fmaf(outm[hh], Wl[t * HID + hh], acc);
        out[g * NCLS + t] = acc;
    }
}

// ---------------------------------------------------------------- launch
extern "C" void kernel_launch(void* const* d_in, const int* in_sizes, int n_in,
                              void* d_out, int out_size, void* d_ws, size_t ws_size,
                              hipStream_t stream) {
    const float* x  = (const float*)d_in[0];
    const int* eidx = (const int*)d_in[1];
    const float* W1 = (const float*)d_in[3];
    const float* b1 = (const float*)d_in[4];
    const float* W2 = (const float*)d_in[5];
    const float* b2 = (const float*)d_in[6];
    const float* Wp = (const float*)d_in[7];
    const float* bp = (const float*)d_in[8];
    const float* Wl = (const float*)d_in[9];
    const float* bl = (const float*)d_in[10];
    float* out = (float*)d_out;

    const int E = in_sizes[1] / 2;
    const int* src = eidx;
    const int* dst = eidx + E;

    // workspace layout: ecnt | gedges | esorted | rp | dinv | H1 | H2 | xpart
    char* w = (char*)d_ws;
    int*            ecnt    = (int*)w;            w += 256;
    int*            gedges  = (int*)w;            w += (size_t)NGRAPH * ECAP * 4;
    unsigned short* esorted = (unsigned short*)w; w += (size_t)NGRAPH * ECAP * 2;
    int*            rp      = (int*)w;            w += (size_t)NGRAPH * (NPER + 1) * 4;
    float*          dinv    = (float*)w;          w += (size_t)N_NODES * 4;
    float*          H1      = (float*)w;          w += (size_t)N_NODES * HID * 4;
    float*          H2      = (float*)w;          w += (size_t)N_NODES * HID * 4;
    float*          xpart   = (float*)w;          w += (size_t)NGRAPH * 8 * KCLUS * HID * 4;

    hipMemsetAsync(ecnt, 0, 256, stream);
    bucket_kernel<<<(E + 1023) / 1024, 256, 0, stream>>>(src, dst, ecnt, gedges, E);
    csr_kernel<<<NGRAPH, 1024, 0, stream>>>(gedges, ecnt, rp, esorted, dinv);

    // conv1 (fused linear+agg): x -> H1
    conv_kernel<IN_F><<<NGRAPH * 8, 512, 0, stream>>>(x, W1, b1, esorted, rp, dinv, H1);
    // conv2: H1 -> H2
    conv_kernel<HID><<<NGRAPH * 8, 512, 0, stream>>>(H1, W2, b2, esorted, rp, dinv, H2);

    // DMoN pooling + classifier
    pool1_kernel<<<NGRAPH * 8, 256, 0, stream>>>(H2, Wp, bp, xpart);
    pool2_kernel<<<NGRAPH, 256, 0, stream>>>(xpart, Wl, bl, out);
}

// Round 13
// 220.884 us; speedup vs baseline: 1.0809x; 1.0809x over previous
//
#include <hip/hip_runtime.h>
#include <cstddef>

#define N_NODES 65536
#define NPER    1024
#define NGRAPH  64
#define HID     64
#define IN_F    128
#define KCLUS   16
#define NCLS    10
#define ECAP    20480   // per-graph capacity incl. 4-alignment padding
#define HSTRIDE 12      // node-major LDS row stride (48 B, 16B-aligned)
#define ZROW    NPER    // index of the all-zero LDS row used by padding entries
#define LIN_BLOCKS 1024 // N_NODES/64 tiles for the linear part of front_kernel

// ---------------------------------------------------------------- front: linear1 (blocks 0..1023) || bucket (blocks 1024..)
// The two are data-independent; merging removes one dispatch + gap and
// co-schedules linear's FMA/LDS work with bucket's atomic latency.
__global__ __launch_bounds__(256) void front_kernel(const float* __restrict__ X,
                                                    const float* __restrict__ W,
                                                    float* __restrict__ Y,
                                                    const int* __restrict__ src,
                                                    const int* __restrict__ dst,
                                                    int* __restrict__ ecnt,
                                                    int* __restrict__ gedges, int E) {
    __shared__ float xsT[64][68];
    __shared__ float wsT[64][68];
    const int t = threadIdx.x;

    if (blockIdx.x >= LIN_BLOCKS) {
        // ---------------- bucket part (LDS aliased onto xsT)
        int* hist = (int*)&xsT[0][0];
        int* base_l = hist + NGRAPH;
        const int e0 = (blockIdx.x - LIN_BLOCKS) * 1024;
        if (t < NGRAPH) hist[t] = 0;
        __syncthreads();

        int gg[4], rr[4], pk[4];
#pragma unroll
        for (int i = 0; i < 4; ++i) {
            int idx = e0 + i * 256 + t;
            if (idx < E) {
                int d = dst[idx], s = src[idx];
                int g = d >> 10;
                gg[i] = g;
                pk[i] = ((d & 1023) << 10) | (s & 1023);
                rr[i] = atomicAdd(&hist[g], 1);
            } else gg[i] = -1;
        }
        __syncthreads();
        if (t < NGRAPH) base_l[t] = atomicAdd(&ecnt[t], hist[t]);
        __syncthreads();
#pragma unroll
        for (int i = 0; i < 4; ++i) {
            if (gg[i] >= 0) {
                int pos = base_l[gg[i]] + rr[i];
                if (pos < ECAP) gedges[gg[i] * ECAP + pos] = pk[i];
            }
        }
        return;
    }

    // ---------------- linear part: Y[64 rows][64] = X[64][IN_F] @ W[64][IN_F]^T
    const size_t row0 = (size_t)blockIdx.x * 64;
    const int r0 = (t >> 4) * 4;
    const int c0 = (t & 15) * 4;
    float acc[4][4] = {};

    for (int kc = 0; kc < IN_F; kc += 64) {
        __syncthreads();
        for (int i = t; i < 1024; i += 256) {
            int row = i >> 4, k4 = (i & 15) << 2;
            float4 v = *(const float4*)(X + (row0 + row) * IN_F + kc + k4);
            xsT[k4 + 0][row] = v.x;
            xsT[k4 + 1][row] = v.y;
            xsT[k4 + 2][row] = v.z;
            xsT[k4 + 3][row] = v.w;
        }
        for (int i = t; i < 1024; i += 256) {
            int col = i >> 4, k4 = (i & 15) << 2;
            float4 v = *(const float4*)(W + col * IN_F + kc + k4);
            wsT[k4 + 0][col] = v.x;
            wsT[k4 + 1][col] = v.y;
            wsT[k4 + 2][col] = v.z;
            wsT[k4 + 3][col] = v.w;
        }
        __syncthreads();

#pragma unroll 8
        for (int k = 0; k < 64; ++k) {
            float4 xv = *(const float4*)&xsT[k][r0];
            float4 wv = *(const float4*)&wsT[k][c0];
            acc[0][0] = fmaf(xv.x, wv.x, acc[0][0]);
            acc[0][1] = fmaf(xv.x, wv.y, acc[0][1]);
            acc[0][2] = fmaf(xv.x, wv.z, acc[0][2]);
            acc[0][3] = fmaf(xv.x, wv.w, acc[0][3]);
            acc[1][0] = fmaf(xv.y, wv.x, acc[1][0]);
            acc[1][1] = fmaf(xv.y, wv.y, acc[1][1]);
            acc[1][2] = fmaf(xv.y, wv.z, acc[1][2]);
            acc[1][3] = fmaf(xv.y, wv.w, acc[1][3]);
            acc[2][0] = fmaf(xv.z, wv.x, acc[2][0]);
            acc[2][1] = fmaf(xv.z, wv.y, acc[2][1]);
            acc[2][2] = fmaf(xv.z, wv.z, acc[2][2]);
            acc[2][3] = fmaf(xv.z, wv.w, acc[2][3]);
            acc[3][0] = fmaf(xv.w, wv.x, acc[3][0]);
            acc[3][1] = fmaf(xv.w, wv.y, acc[3][1]);
            acc[3][2] = fmaf(xv.w, wv.z, acc[3][2]);
            acc[3][3] = fmaf(xv.w, wv.w, acc[3][3]);
        }
    }

#pragma unroll
    for (int i = 0; i < 4; ++i) {
        float4 v = make_float4(acc[i][0], acc[i][1], acc[i][2], acc[i][3]);
        *(float4*)(Y + (row0 + r0 + i) * HID + c0) = v;
    }
}

// ---------------------------------------------------------------- per-graph CSR build in LDS (shuffle-scan)
__global__ __launch_bounds__(1024) void csr_kernel(const int* __restrict__ gedges,
                                                   const int* __restrict__ ecnt,
                                                   int* __restrict__ rp,
                                                   unsigned short* __restrict__ esorted,
                                                   float* __restrict__ dinv) {
    __shared__ int hist[NPER];
    __shared__ int wsum[16];
    const int g = blockIdx.x, t = threadIdx.x;
    const int lane = t & 63, wid = t >> 6;
    const int ec = ecnt[g];
    const int* ge = gedges + (size_t)g * ECAP;

    hist[t] = 0;
    __syncthreads();
    for (int i = t; i < ec; i += 1024) atomicAdd(&hist[ge[i] >> 10], 1);
    __syncthreads();

    const int h0 = hist[t];
    const int pd = (h0 + 3) & ~3;   // padded degree
    int v = pd;
#pragma unroll
    for (int off = 1; off < 64; off <<= 1) {
        int x = __shfl_up(v, off, 64);
        if (lane >= off) v += x;
    }
    if (lane == 63) wsum[wid] = v;
    __syncthreads();
    if (wid == 0) {
        int wv = (lane < 16) ? wsum[lane] : 0;
#pragma unroll
        for (int off = 1; off < 16; off <<= 1) {
            int x = __shfl_up(wv, off, 64);
            if (lane >= off) wv += x;
        }
        if (lane < 16) wsum[lane] = wv;
    }
    __syncthreads();
    const int incl = v + (wid > 0 ? wsum[wid - 1] : 0);
    const int excl = incl - pd;

    rp[g * (NPER + 1) + t] = excl;
    if (t == NPER - 1) rp[g * (NPER + 1) + NPER] = incl;
    dinv[g * NPER + t] = rsqrtf((float)h0 + 1.0f);

    hist[t] = excl;   // scatter cursor
    __syncthreads();

    unsigned short* es = esorted + (size_t)g * ECAP;
    for (int i = t; i < ec; i += 1024) {
        int pk = ge[i];
        int pos = atomicAdd(&hist[pk >> 10], 1);
        es[pos] = (unsigned short)(pk & 1023);
    }
    __syncthreads();
    for (int q = excl + h0; q < excl + pd; ++q) es[q] = (unsigned short)ZROW;
}

// ---------------------------------------------------------------- dense linear (used for conv2): Y = X @ W^T
template <int K>
__global__ __launch_bounds__(256) void linear_kernel(const float* __restrict__ X,
                                                     const float* __restrict__ W,
                                                     float* __restrict__ Y) {
    __shared__ float xsT[64][68];
    __shared__ float wsT[64][68];
    const int t = threadIdx.x;
    const size_t row0 = (size_t)blockIdx.x * 64;
    const int r0 = (t >> 4) * 4;
    const int c0 = (t & 15) * 4;
    float acc[4][4] = {};

    for (int kc = 0; kc < K; kc += 64) {
        __syncthreads();
        for (int i = t; i < 1024; i += 256) {
            int row = i >> 4, k4 = (i & 15) << 2;
            float4 v = *(const float4*)(X + (row0 + row) * K + kc + k4);
            xsT[k4 + 0][row] = v.x;
            xsT[k4 + 1][row] = v.y;
            xsT[k4 + 2][row] = v.z;
            xsT[k4 + 3][row] = v.w;
        }
        for (int i = t; i < 1024; i += 256) {
            int col = i >> 4, k4 = (i & 15) << 2;
            float4 v = *(const float4*)(W + col * K + kc + k4);
            wsT[k4 + 0][col] = v.x;
            wsT[k4 + 1][col] = v.y;
            wsT[k4 + 2][col] = v.z;
            wsT[k4 + 3][col] = v.w;
        }
        __syncthreads();

#pragma unroll 8
        for (int k = 0; k < 64; ++k) {
            float4 xv = *(const float4*)&xsT[k][r0];
            float4 wv = *(const float4*)&wsT[k][c0];
            acc[0][0] = fmaf(xv.x, wv.x, acc[0][0]);
            acc[0][1] = fmaf(xv.x, wv.y, acc[0][1]);
            acc[0][2] = fmaf(xv.x, wv.z, acc[0][2]);
            acc[0][3] = fmaf(xv.x, wv.w, acc[0][3]);
            acc[1][0] = fmaf(xv.y, wv.x, acc[1][0]);
            acc[1][1] = fmaf(xv.y, wv.y, acc[1][1]);
            acc[1][2] = fmaf(xv.y, wv.z, acc[1][2]);
            acc[1][3] = fmaf(xv.y, wv.w, acc[1][3]);
            acc[2][0] = fmaf(xv.z, wv.x, acc[2][0]);
            acc[2][1] = fmaf(xv.z, wv.y, acc[2][1]);
            acc[2][2] = fmaf(xv.z, wv.z, acc[2][2]);
            acc[2][3] = fmaf(xv.z, wv.w, acc[2][3]);
            acc[3][0] = fmaf(xv.w, wv.x, acc[3][0]);
            acc[3][1] = fmaf(xv.w, wv.y, acc[3][1]);
            acc[3][2] = fmaf(xv.w, wv.z, acc[3][2]);
            acc[3][3] = fmaf(xv.w, wv.w, acc[3][3]);
        }
    }

#pragma unroll
    for (int i = 0; i < 4; ++i) {
        float4 v = make_float4(acc[i][0], acc[i][1], acc[i][2], acc[i][3]);
        *(float4*)(Y + (row0 + r0 + i) * HID + c0) = v;
    }
}

// ---------------------------------------------------------------- pull-based aggregation, fused self-loop+bias+relu
__global__ __launch_bounds__(512) void agg_kernel(const float* __restrict__ h,
                                                  const unsigned short* __restrict__ esorted,
                                                  const int* __restrict__ rp,
                                                  const float* __restrict__ dinv,
                                                  const float* __restrict__ bias,
                                                  float* __restrict__ outp) {
    __shared__ float Hs[(NPER + 1) * HSTRIDE];
    __shared__ float dl[NPER];
    const int g = blockIdx.x & 63;          // same-XCD grouping (%8 invariant)
    const int f0 = (blockIdx.x >> 6) * 8;
    const int t = threadIdx.x;
    const int base = g * NPER;

    for (int r = t; r < NPER; r += 512) {
        const float* hp = h + (size_t)(base + r) * HID + f0;
        float4 a = *(const float4*)hp;
        float4 b = *(const float4*)(hp + 4);
        float dv = dinv[base + r];
        dl[r] = dv;
        float* row = &Hs[r * HSTRIDE];
        *(float4*)row = make_float4(a.x * dv, a.y * dv, a.z * dv, a.w * dv);
        *(float4*)(row + 4) = make_float4(b.x * dv, b.y * dv, b.z * dv, b.w * dv);
    }
    if (t < HSTRIDE) Hs[ZROW * HSTRIDE + t] = 0.f;
    float bb[8];
#pragma unroll
    for (int j = 0; j < 8; ++j) bb[j] = bias[f0 + j];
    const unsigned short* es = esorted + (size_t)g * ECAP;
    const int* rpg = rp + g * (NPER + 1);
    __syncthreads();

    for (int ld = t; ld < NPER; ld += 512) {
        int p = rpg[ld];
        const int pe = rpg[ld + 1];
        const float* srow = &Hs[ld * HSTRIDE];
        float4 acc0 = *(const float4*)srow;
        float4 acc1 = *(const float4*)(srow + 4);
        float4 bcc0 = make_float4(0.f, 0.f, 0.f, 0.f);
        float4 bcc1 = make_float4(0.f, 0.f, 0.f, 0.f);

        for (; p < pe; p += 4) {
            uint2 w4 = *(const uint2*)(es + p);
            const float* r0 = &Hs[(int)(w4.x & 0xFFFFu) * HSTRIDE];
            const float* r1 = &Hs[(int)(w4.x >> 16) * HSTRIDE];
            const float* r2 = &Hs[(int)(w4.y & 0xFFFFu) * HSTRIDE];
            const float* r3 = &Hs[(int)(w4.y >> 16) * HSTRIDE];
            float4 a0 = *(const float4*)r0, a1 = *(const float4*)(r0 + 4);
            float4 b0 = *(const float4*)r1, b1 = *(const float4*)(r1 + 4);
            float4 c0v = *(const float4*)r2, c1v = *(const float4*)(r2 + 4);
            float4 d0 = *(const float4*)r3, d1 = *(const float4*)(r3 + 4);
            acc0.x += a0.x; acc0.y += a0.y; acc0.z += a0.z; acc0.w += a0.w;
            acc1.x += a1.x; acc1.y += a1.y; acc1.z += a1.z; acc1.w += a1.w;
            bcc0.x += b0.x; bcc0.y += b0.y; bcc0.z += b0.z; bcc0.w += b0.w;
            bcc1.x += b1.x; bcc1.y += b1.y; bcc1.z += b1.z; bcc1.w += b1.w;
            acc0.x += c0v.x; acc0.y += c0v.y; acc0.z += c0v.z; acc0.w += c0v.w;
            acc1.x += c1v.x; acc1.y += c1v.y; acc1.z += c1v.z; acc1.w += c1v.w;
            bcc0.x += d0.x; bcc0.y += d0.y; bcc0.z += d0.z; bcc0.w += d0.w;
            bcc1.x += d1.x; bcc1.y += d1.y; bcc1.z += d1.z; bcc1.w += d1.w;
        }
        acc0.x += bcc0.x; acc0.y += bcc0.y; acc0.z += bcc0.z; acc0.w += bcc0.w;
        acc1.x += bcc1.x; acc1.y += bcc1.y; acc1.z += bcc1.z; acc1.w += bcc1.w;

        const float dv = dl[ld];
        float4 o0, o1;
        o0.x = fmaxf(fmaf(acc0.x, dv, bb[0]), 0.f);
        o0.y = fmaxf(fmaf(acc0.y, dv, bb[1]), 0.f);
        o0.z = fmaxf(fmaf(acc0.z, dv, bb[2]), 0.f);
        o0.w = fmaxf(fmaf(acc0.w, dv, bb[3]), 0.f);
        o1.x = fmaxf(fmaf(acc1.x, dv, bb[4]), 0.f);
        o1.y = fmaxf(fmaf(acc1.y, dv, bb[5]), 0.f);
        o1.z = fmaxf(fmaf(acc1.z, dv, bb[6]), 0.f);
        o1.w = fmaxf(fmaf(acc1.w, dv, bb[7]), 0.f);
        float* op = outp + (size_t)(base + ld) * HID + f0;
        *(float4*)op = o0;
        *(float4*)(op + 4) = o1;
    }
}

// ---------------------------------------------------------------- fused DMoN phase 1: softmax assignment + partial cluster sums
__global__ __launch_bounds__(256) void pool1_kernel(const float* __restrict__ h,
                                                    const float* __restrict__ Wp,
                                                    const float* __restrict__ bp,
                                                    float* __restrict__ xpart) {
    __shared__ float xs[128][HID + 1];
    __shared__ float ss[128][KCLUS + 1];
    __shared__ float wp[KCLUS][HID];
    __shared__ float bps[KCLUS];
    const int g = blockIdx.x >> 3;
    const int c = blockIdx.x & 7;
    const int t = threadIdx.x;
    const float* hb = h + ((size_t)g * NPER + c * 128) * HID;

    for (int i = t; i < 128 * HID / 4; i += 256) {
        float4 v = ((const float4*)hb)[i];
        int row = i >> 4, col = (i & 15) * 4;
        xs[row][col] = v.x; xs[row][col + 1] = v.y; xs[row][col + 2] = v.z; xs[row][col + 3] = v.w;
    }
    for (int i = t; i < KCLUS * HID; i += 256) wp[i >> 6][i & 63] = Wp[i];
    if (t < KCLUS) bps[t] = bp[t];
    __syncthreads();

    if (t < 128) {
        float lg[KCLUS];
        float mx = -1e30f;
#pragma unroll
        for (int k = 0; k < KCLUS; ++k) {
            float a = bps[k];
#pragma unroll 8
            for (int hh = 0; hh < HID; ++hh) a = fmaf(xs[t][hh], wp[k][hh], a);
            lg[k] = a;
            mx = fmaxf(mx, a);
        }
        float sum = 0.f;
#pragma unroll
        for (int k = 0; k < KCLUS; ++k) {
            lg[k] = __expf(lg[k] - mx);
            sum += lg[k];
        }
        float inv = 1.0f / sum;
#pragma unroll
        for (int k = 0; k < KCLUS; ++k) ss[t][k] = lg[k] * inv;
    }
    __syncthreads();

    const int hcol = t & 63;
    const int k0 = (t >> 6) * 4;
    float a0 = 0.f, a1 = 0.f, a2 = 0.f, a3 = 0.f;
#pragma unroll 8
    for (int n = 0; n < 128; ++n) {
        float xv = xs[n][hcol];
        a0 = fmaf(ss[n][k0 + 0], xv, a0);
        a1 = fmaf(ss[n][k0 + 1], xv, a1);
        a2 = fmaf(ss[n][k0 + 2], xv, a2);
        a3 = fmaf(ss[n][k0 + 3], xv, a3);
    }
    float* xp = xpart + (((size_t)(g * 8 + c)) * KCLUS + k0) * HID + hcol;
    xp[0] = a0; xp[HID] = a1; xp[2 * HID] = a2; xp[3 * HID] = a3;
}

// ---------------------------------------------------------------- DMoN phase 2: reduce partials, selu, mean, classifier
__global__ __launch_bounds__(256) void pool2_kernel(const float* __restrict__ xpart,
                                                    const float* __restrict__ Wl,
                                                    const float* __restrict__ bl,
                                                    float* __restrict__ out) {
    __shared__ float xp[KCLUS][HID + 1];
    __shared__ float outm[HID];
    const int g = blockIdx.x;
    const int t = threadIdx.x;
    const int hcol = t & 63;
    const int k0 = (t >> 6) * 4;
    const float* base = xpart + (size_t)g * 8 * KCLUS * HID;

    float a[4] = {};
#pragma unroll
    for (int c = 0; c < 8; ++c)
#pragma unroll
        for (int j = 0; j < 4; ++j)
            a[j] += base[(c * KCLUS + k0 + j) * HID + hcol];

    const float sc = 1.0507009873554805f, al = 1.6732632423543772f;
#pragma unroll
    for (int j = 0; j < 4; ++j) {
        float v = a[j];
        xp[k0 + j][hcol] = v > 0.f ? sc * v : sc * al * (__expf(v) - 1.f);
    }
    __syncthreads();

    if (t < HID) {
        float m = 0.f;
#pragma unroll
        for (int k = 0; k < KCLUS; ++k) m += xp[k][t];
        outm[t] = m * (1.0f / KCLUS);
    }
    __syncthreads();

    if (t < NCLS) {
        float acc = bl[t];
#pragma unroll 8
        for (int hh = 0; hh < HID; ++hh) acc = fmaf(outm[hh], Wl[t * HID + hh], acc);
        out[g * NCLS + t] = acc;
    }
}

// ---------------------------------------------------------------- launch
extern "C" void kernel_launch(void* const* d_in, const int* in_sizes, int n_in,
                              void* d_out, int out_size, void* d_ws, size_t ws_size,
                              hipStream_t stream) {
    const float* x  = (const float*)d_in[0];
    const int* eidx = (const int*)d_in[1];
    const float* W1 = (const float*)d_in[3];
    const float* b1 = (const float*)d_in[4];
    const float* W2 = (const float*)d_in[5];
    const float* b2 = (const float*)d_in[6];
    const float* Wp = (const float*)d_in[7];
    const float* bp = (const float*)d_in[8];
    const float* Wl = (const float*)d_in[9];
    const float* bl = (const float*)d_in[10];
    float* out = (float*)d_out;

    const int E = in_sizes[1] / 2;
    const int* src = eidx;
    const int* dst = eidx + E;

    // workspace layout: ecnt | gedges | esorted | rp | dinv | A | Bf | xpart
    char* w = (char*)d_ws;
    int*            ecnt    = (int*)w;            w += 256;
    int*            gedges  = (int*)w;            w += (size_t)NGRAPH * ECAP * 4;
    unsigned short* esorted = (unsigned short*)w; w += (size_t)NGRAPH * ECAP * 2;
    int*            rp      = (int*)w;            w += (size_t)NGRAPH * (NPER + 1) * 4;
    float*          dinv    = (float*)w;          w += (size_t)N_NODES * 4;
    float*          A       = (float*)w;          w += (size_t)N_NODES * HID * 4;
    float*          Bf      = (float*)w;          w += (size_t)N_NODES * HID * 4;
    float*          xpart   = (float*)w;          w += (size_t)NGRAPH * 8 * KCLUS * HID * 4;

    hipMemsetAsync(ecnt, 0, 256, stream);

    // linear1 || bucket (independent) in one dispatch
    const int nbucket = (E + 1023) / 1024;
    front_kernel<<<LIN_BLOCKS + nbucket, 256, 0, stream>>>(x, W1, A, src, dst, ecnt, gedges, E);
    csr_kernel<<<NGRAPH, 1024, 0, stream>>>(gedges, ecnt, rp, esorted, dinv);

    // conv1 aggregation: A -> Bf
    agg_kernel<<<NGRAPH * 8, 512, 0, stream>>>(A, esorted, rp, dinv, b1, Bf);

    // conv2: Bf -> A -> Bf
    linear_kernel<HID><<<N_NODES / 64, 256, 0, stream>>>(Bf, W2, A);
    agg_kernel<<<NGRAPH * 8, 512, 0, stream>>>(A, esorted, rp, dinv, b2, Bf);

    // DMoN pooling + classifier
    pool1_kernel<<<NGRAPH * 8, 256, 0, stream>>>(Bf, Wp, bp, xpart);
    pool2_kernel<<<NGRAPH, 256, 0, stream>>>(xpart, Wl, bl, out);
}

// Round 14
// 214.743 us; speedup vs baseline: 1.1118x; 1.0286x over previous
//
#include <hip/hip_runtime.h>
#include <cstddef>

#define N_NODES 65536
#define NPER    1024
#define NGRAPH  64
#define HID     64
#define IN_F    128
#define KCLUS   16
#define NCLS    10
#define ECAP    20480   // per-graph capacity incl. 4-alignment padding
#define HSTRIDE 12      // node-major LDS row stride (48 B, 16B-aligned)
#define ZROW    NPER    // index of the all-zero LDS row used by padding entries
#define LIN_BLOCKS 512  // N_NODES/128 tiles for the linear part of front_kernel

// ================================================================ GEMM tile core
// 128 rows x 64 cols per block, 256 threads, 4x8 per thread (rows strided 32,
// cols strided 8). Row-major LDS both operands: staging is natural/coalesced
// (conflict-free), reads are 12x ds_read_b128 per 128 FMA with 8-consecutive-row
// bank pattern (conflict-free, 8-way broadcast). VALU-bound by design.
template <int K>
__device__ __forceinline__ void gemm_tile(const float* __restrict__ X,
                                          const float* __restrict__ W,
                                          float* __restrict__ Y,
                                          float (*xs)[68], float (*ws)[68],
                                          int block, int t) {
    const size_t row0 = (size_t)block * 128;
    const int rbase = t >> 3;   // 0..31
    const int cbase = t & 7;    // 0..7
    float acc[4][8] = {};

    for (int kc = 0; kc < K; kc += 64) {
        __syncthreads();
        for (int i = t; i < 128 * 16; i += 256) {   // X tile: 128 rows x 16 float4
            int row = i >> 4, k4 = (i & 15) << 2;
            *(float4*)&xs[row][k4] = *(const float4*)(X + (row0 + row) * K + kc + k4);
        }
        for (int i = t; i < 64 * 16; i += 256) {    // W tile: 64 rows x 16 float4
            int col = i >> 4, k4 = (i & 15) << 2;
            *(float4*)&ws[col][k4] = *(const float4*)(W + col * K + kc + k4);
        }
        __syncthreads();

#pragma unroll 4
        for (int k4 = 0; k4 < 64; k4 += 4) {
            float4 xr[4], wr[8];
#pragma unroll
            for (int rr = 0; rr < 4; ++rr) xr[rr] = *(const float4*)&xs[rbase + 32 * rr][k4];
#pragma unroll
            for (int cc = 0; cc < 8; ++cc) wr[cc] = *(const float4*)&ws[cbase + 8 * cc][k4];
#pragma unroll
            for (int rr = 0; rr < 4; ++rr)
#pragma unroll
                for (int cc = 0; cc < 8; ++cc) {
                    acc[rr][cc] = fmaf(xr[rr].x, wr[cc].x, acc[rr][cc]);
                    acc[rr][cc] = fmaf(xr[rr].y, wr[cc].y, acc[rr][cc]);
                    acc[rr][cc] = fmaf(xr[rr].z, wr[cc].z, acc[rr][cc]);
                    acc[rr][cc] = fmaf(xr[rr].w, wr[cc].w, acc[rr][cc]);
                }
        }
    }

#pragma unroll
    for (int rr = 0; rr < 4; ++rr)
#pragma unroll
        for (int cc = 0; cc < 8; ++cc)
            Y[(row0 + rbase + 32 * rr) * HID + cbase + 8 * cc] = acc[rr][cc];
}

// ---------------------------------------------------------------- front: linear1 (blocks 0..511) || bucket (blocks 512..)
__global__ __launch_bounds__(256) void front_kernel(const float* __restrict__ X,
                                                    const float* __restrict__ W,
                                                    float* __restrict__ Y,
                                                    const int* __restrict__ src,
                                                    const int* __restrict__ dst,
                                                    int* __restrict__ ecnt,
                                                    int* __restrict__ gedges, int E) {
    __shared__ float xs[128][68];
    __shared__ float ws[64][68];
    const int t = threadIdx.x;

    if (blockIdx.x >= LIN_BLOCKS) {
        // ---------------- bucket part (LDS aliased onto xs)
        int* hist = (int*)&xs[0][0];
        int* base_l = hist + NGRAPH;
        const int e0 = (blockIdx.x - LIN_BLOCKS) * 1024;
        if (t < NGRAPH) hist[t] = 0;
        __syncthreads();

        int gg[4], rr[4], pk[4];
#pragma unroll
        for (int i = 0; i < 4; ++i) {
            int idx = e0 + i * 256 + t;
            if (idx < E) {
                int d = dst[idx], s = src[idx];
                int g = d >> 10;
                gg[i] = g;
                pk[i] = ((d & 1023) << 10) | (s & 1023);
                rr[i] = atomicAdd(&hist[g], 1);
            } else gg[i] = -1;
        }
        __syncthreads();
        if (t < NGRAPH) base_l[t] = atomicAdd(&ecnt[t], hist[t]);
        __syncthreads();
#pragma unroll
        for (int i = 0; i < 4; ++i) {
            if (gg[i] >= 0) {
                int pos = base_l[gg[i]] + rr[i];
                if (pos < ECAP) gedges[gg[i] * ECAP + pos] = pk[i];
            }
        }
        return;
    }

    gemm_tile<IN_F>(X, W, Y, xs, ws, blockIdx.x, t);
}

// ---------------------------------------------------------------- dense linear (conv2): Y = X @ W^T
template <int K>
__global__ __launch_bounds__(256) void linear_kernel(const float* __restrict__ X,
                                                     const float* __restrict__ W,
                                                     float* __restrict__ Y) {
    __shared__ float xs[128][68];
    __shared__ float ws[64][68];
    gemm_tile<K>(X, W, Y, xs, ws, blockIdx.x, threadIdx.x);
}

// ---------------------------------------------------------------- per-graph CSR build in LDS (shuffle-scan)
__global__ __launch_bounds__(1024) void csr_kernel(const int* __restrict__ gedges,
                                                   const int* __restrict__ ecnt,
                                                   int* __restrict__ rp,
                                                   unsigned short* __restrict__ esorted,
                                                   float* __restrict__ dinv) {
    __shared__ int hist[NPER];
    __shared__ int wsum[16];
    const int g = blockIdx.x, t = threadIdx.x;
    const int lane = t & 63, wid = t >> 6;
    const int ec = ecnt[g];
    const int* ge = gedges + (size_t)g * ECAP;

    hist[t] = 0;
    __syncthreads();
    for (int i = t; i < ec; i += 1024) atomicAdd(&hist[ge[i] >> 10], 1);
    __syncthreads();

    const int h0 = hist[t];
    const int pd = (h0 + 3) & ~3;   // padded degree
    int v = pd;
#pragma unroll
    for (int off = 1; off < 64; off <<= 1) {
        int x = __shfl_up(v, off, 64);
        if (lane >= off) v += x;
    }
    if (lane == 63) wsum[wid] = v;
    __syncthreads();
    if (wid == 0) {
        int wv = (lane < 16) ? wsum[lane] : 0;
#pragma unroll
        for (int off = 1; off < 16; off <<= 1) {
            int x = __shfl_up(wv, off, 64);
            if (lane >= off) wv += x;
        }
        if (lane < 16) wsum[lane] = wv;
    }
    __syncthreads();
    const int incl = v + (wid > 0 ? wsum[wid - 1] : 0);
    const int excl = incl - pd;

    rp[g * (NPER + 1) + t] = excl;
    if (t == NPER - 1) rp[g * (NPER + 1) + NPER] = incl;
    dinv[g * NPER + t] = rsqrtf((float)h0 + 1.0f);

    hist[t] = excl;   // scatter cursor
    __syncthreads();

    unsigned short* es = esorted + (size_t)g * ECAP;
    for (int i = t; i < ec; i += 1024) {
        int pk = ge[i];
        int pos = atomicAdd(&hist[pk >> 10], 1);
        es[pos] = (unsigned short)(pk & 1023);
    }
    __syncthreads();
    for (int q = excl + h0; q < excl + pd; ++q) es[q] = (unsigned short)ZROW;
}

// ---------------------------------------------------------------- pull-based aggregation, fused self-loop+bias+relu
__global__ __launch_bounds__(512) void agg_kernel(const float* __restrict__ h,
                                                  const unsigned short* __restrict__ esorted,
                                                  const int* __restrict__ rp,
                                                  const float* __restrict__ dinv,
                                                  const float* __restrict__ bias,
                                                  float* __restrict__ outp) {
    __shared__ float Hs[(NPER + 1) * HSTRIDE];
    __shared__ float dl[NPER];
    const int g = blockIdx.x & 63;          // same-XCD grouping (%8 invariant)
    const int f0 = (blockIdx.x >> 6) * 8;
    const int t = threadIdx.x;
    const int base = g * NPER;

    for (int r = t; r < NPER; r += 512) {
        const float* hp = h + (size_t)(base + r) * HID + f0;
        float4 a = *(const float4*)hp;
        float4 b = *(const float4*)(hp + 4);
        float dv = dinv[base + r];
        dl[r] = dv;
        float* row = &Hs[r * HSTRIDE];
        *(float4*)row = make_float4(a.x * dv, a.y * dv, a.z * dv, a.w * dv);
        *(float4*)(row + 4) = make_float4(b.x * dv, b.y * dv, b.z * dv, b.w * dv);
    }
    if (t < HSTRIDE) Hs[ZROW * HSTRIDE + t] = 0.f;
    float bb[8];
#pragma unroll
    for (int j = 0; j < 8; ++j) bb[j] = bias[f0 + j];
    const unsigned short* es = esorted + (size_t)g * ECAP;
    const int* rpg = rp + g * (NPER + 1);
    __syncthreads();

    for (int ld = t; ld < NPER; ld += 512) {
        int p = rpg[ld];
        const int pe = rpg[ld + 1];
        const float* srow = &Hs[ld * HSTRIDE];
        float4 acc0 = *(const float4*)srow;
        float4 acc1 = *(const float4*)(srow + 4);
        float4 bcc0 = make_float4(0.f, 0.f, 0.f, 0.f);
        float4 bcc1 = make_float4(0.f, 0.f, 0.f, 0.f);

        for (; p < pe; p += 4) {
            uint2 w4 = *(const uint2*)(es + p);
            const float* r0 = &Hs[(int)(w4.x & 0xFFFFu) * HSTRIDE];
            const float* r1 = &Hs[(int)(w4.x >> 16) * HSTRIDE];
            const float* r2 = &Hs[(int)(w4.y & 0xFFFFu) * HSTRIDE];
            const float* r3 = &Hs[(int)(w4.y >> 16) * HSTRIDE];
            float4 a0 = *(const float4*)r0, a1 = *(const float4*)(r0 + 4);
            float4 b0 = *(const float4*)r1, b1 = *(const float4*)(r1 + 4);
            float4 c0v = *(const float4*)r2, c1v = *(const float4*)(r2 + 4);
            float4 d0 = *(const float4*)r3, d1 = *(const float4*)(r3 + 4);
            acc0.x += a0.x; acc0.y += a0.y; acc0.z += a0.z; acc0.w += a0.w;
            acc1.x += a1.x; acc1.y += a1.y; acc1.z += a1.z; acc1.w += a1.w;
            bcc0.x += b0.x; bcc0.y += b0.y; bcc0.z += b0.z; bcc0.w += b0.w;
            bcc1.x += b1.x; bcc1.y += b1.y; bcc1.z += b1.z; bcc1.w += b1.w;
            acc0.x += c0v.x; acc0.y += c0v.y; acc0.z += c0v.z; acc0.w += c0v.w;
            acc1.x += c1v.x; acc1.y += c1v.y; acc1.z += c1v.z; acc1.w += c1v.w;
            bcc0.x += d0.x; bcc0.y += d0.y; bcc0.z += d0.z; bcc0.w += d0.w;
            bcc1.x += d1.x; bcc1.y += d1.y; bcc1.z += d1.z; bcc1.w += d1.w;
        }
        acc0.x += bcc0.x; acc0.y += bcc0.y; acc0.z += bcc0.z; acc0.w += bcc0.w;
        acc1.x += bcc1.x; acc1.y += bcc1.y; acc1.z += bcc1.z; acc1.w += bcc1.w;

        const float dv = dl[ld];
        float4 o0, o1;
        o0.x = fmaxf(fmaf(acc0.x, dv, bb[0]), 0.f);
        o0.y = fmaxf(fmaf(acc0.y, dv, bb[1]), 0.f);
        o0.z = fmaxf(fmaf(acc0.z, dv, bb[2]), 0.f);
        o0.w = fmaxf(fmaf(acc0.w, dv, bb[3]), 0.f);
        o1.x = fmaxf(fmaf(acc1.x, dv, bb[4]), 0.f);
        o1.y = fmaxf(fmaf(acc1.y, dv, bb[5]), 0.f);
        o1.z = fmaxf(fmaf(acc1.z, dv, bb[6]), 0.f);
        o1.w = fmaxf(fmaf(acc1.w, dv, bb[7]), 0.f);
        float* op = outp + (size_t)(base + ld) * HID + f0;
        *(float4*)op = o0;
        *(float4*)(op + 4) = o1;
    }
}

// ---------------------------------------------------------------- fused DMoN phase 1: softmax assignment + partial cluster sums
__global__ __launch_bounds__(256) void pool1_kernel(const float* __restrict__ h,
                                                    const float* __restrict__ Wp,
                                                    const float* __restrict__ bp,
                                                    float* __restrict__ xpart) {
    __shared__ float xs[128][HID + 1];
    __shared__ float ss[128][KCLUS + 1];
    __shared__ float wp[KCLUS][HID];
    __shared__ float bps[KCLUS];
    const int g = blockIdx.x >> 3;
    const int c = blockIdx.x & 7;
    const int t = threadIdx.x;
    const float* hb = h + ((size_t)g * NPER + c * 128) * HID;

    for (int i = t; i < 128 * HID / 4; i += 256) {
        float4 v = ((const float4*)hb)[i];
        int row = i >> 4, col = (i & 15) * 4;
        xs[row][col] = v.x; xs[row][col + 1] = v.y; xs[row][col + 2] = v.z; xs[row][col + 3] = v.w;
    }
    for (int i = t; i < KCLUS * HID; i += 256) wp[i >> 6][i & 63] = Wp[i];
    if (t < KCLUS) bps[t] = bp[t];
    __syncthreads();

    if (t < 128) {
        float lg[KCLUS];
        float mx = -1e30f;
#pragma unroll
        for (int k = 0; k < KCLUS; ++k) {
            float a = bps[k];
#pragma unroll 8
            for (int hh = 0; hh < HID; ++hh) a = fmaf(xs[t][hh], wp[k][hh], a);
            lg[k] = a;
            mx = fmaxf(mx, a);
        }
        float sum = 0.f;
#pragma unroll
        for (int k = 0; k < KCLUS; ++k) {
            lg[k] = __expf(lg[k] - mx);
            sum += lg[k];
        }
        float inv = 1.0f / sum;
#pragma unroll
        for (int k = 0; k < KCLUS; ++k) ss[t][k] = lg[k] * inv;
    }
    __syncthreads();

    const int hcol = t & 63;
    const int k0 = (t >> 6) * 4;
    float a0 = 0.f, a1 = 0.f, a2 = 0.f, a3 = 0.f;
#pragma unroll 8
    for (int n = 0; n < 128; ++n) {
        float xv = xs[n][hcol];
        a0 = fmaf(ss[n][k0 + 0], xv, a0);
        a1 = fmaf(ss[n][k0 + 1], xv, a1);
        a2 = fmaf(ss[n][k0 + 2], xv, a2);
        a3 = fmaf(ss[n][k0 + 3], xv, a3);
    }
    float* xp = xpart + (((size_t)(g * 8 + c)) * KCLUS + k0) * HID + hcol;
    xp[0] = a0; xp[HID] = a1; xp[2 * HID] = a2; xp[3 * HID] = a3;
}

// ---------------------------------------------------------------- DMoN phase 2: reduce partials, selu, mean, classifier
__global__ __launch_bounds__(256) void pool2_kernel(const float* __restrict__ xpart,
                                                    const float* __restrict__ Wl,
                                                    const float* __restrict__ bl,
                                                    float* __restrict__ out) {
    __shared__ float xp[KCLUS][HID + 1];
    __shared__ float outm[HID];
    const int g = blockIdx.x;
    const int t = threadIdx.x;
    const int hcol = t & 63;
    const int k0 = (t >> 6) * 4;
    const float* base = xpart + (size_t)g * 8 * KCLUS * HID;

    float a[4] = {};
#pragma unroll
    for (int c = 0; c < 8; ++c)
#pragma unroll
        for (int j = 0; j < 4; ++j)
            a[j] += base[(c * KCLUS + k0 + j) * HID + hcol];

    const float sc = 1.0507009873554805f, al = 1.6732632423543772f;
#pragma unroll
    for (int j = 0; j < 4; ++j) {
        float v = a[j];
        xp[k0 + j][hcol] = v > 0.f ? sc * v : sc * al * (__expf(v) - 1.f);
    }
    __syncthreads();

    if (t < HID) {
        float m = 0.f;
#pragma unroll
        for (int k = 0; k < KCLUS; ++k) m += xp[k][t];
        outm[t] = m * (1.0f / KCLUS);
    }
    __syncthreads();

    if (t < NCLS) {
        float acc = bl[t];
#pragma unroll 8
        for (int hh = 0; hh < HID; ++hh) acc = fmaf(outm[hh], Wl[t * HID + hh], acc);
        out[g * NCLS + t] = acc;
    }
}

// ---------------------------------------------------------------- launch
extern "C" void kernel_launch(void* const* d_in, const int* in_sizes, int n_in,
                              void* d_out, int out_size, void* d_ws, size_t ws_size,
                              hipStream_t stream) {
    const float* x  = (const float*)d_in[0];
    const int* eidx = (const int*)d_in[1];
    const float* W1 = (const float*)d_in[3];
    const float* b1 = (const float*)d_in[4];
    const float* W2 = (const float*)d_in[5];
    const float* b2 = (const float*)d_in[6];
    const float* Wp = (const float*)d_in[7];
    const float* bp = (const float*)d_in[8];
    const float* Wl = (const float*)d_in[9];
    const float* bl = (const float*)d_in[10];
    float* out = (float*)d_out;

    const int E = in_sizes[1] / 2;
    const int* src = eidx;
    const int* dst = eidx + E;

    // workspace layout: ecnt | gedges | esorted | rp | dinv | A | Bf | xpart
    char* w = (char*)d_ws;
    int*            ecnt    = (int*)w;            w += 256;
    int*            gedges  = (int*)w;            w += (size_t)NGRAPH * ECAP * 4;
    unsigned short* esorted = (unsigned short*)w; w += (size_t)NGRAPH * ECAP * 2;
    int*            rp      = (int*)w;            w += (size_t)NGRAPH * (NPER + 1) * 4;
    float*          dinv    = (float*)w;          w += (size_t)N_NODES * 4;
    float*          A       = (float*)w;          w += (size_t)N_NODES * HID * 4;
    float*          Bf      = (float*)w;          w += (size_t)N_NODES * HID * 4;
    float*          xpart   = (float*)w;          w += (size_t)NGRAPH * 8 * KCLUS * HID * 4;

    hipMemsetAsync(ecnt, 0, 256, stream);

    // linear1 || bucket (independent) in one dispatch
    const int nbucket = (E + 1023) / 1024;
    front_kernel<<<LIN_BLOCKS + nbucket, 256, 0, stream>>>(x, W1, A, src, dst, ecnt, gedges, E);
    csr_kernel<<<NGRAPH, 1024, 0, stream>>>(gedges, ecnt, rp, esorted, dinv);

    // conv1 aggregation: A -> Bf
    agg_kernel<<<NGRAPH * 8, 512, 0, stream>>>(A, esorted, rp, dinv, b1, Bf);

    // conv2: Bf -> A -> Bf
    linear_kernel<HID><<<N_NODES / 128, 256, 0, stream>>>(Bf, W2, A);
    agg_kernel<<<NGRAPH * 8, 512, 0, stream>>>(A, esorted, rp, dinv, b2, Bf);

    // DMoN pooling + classifier
    pool1_kernel<<<NGRAPH * 8, 256, 0, stream>>>(Bf, Wp, bp, xpart);
    pool2_kernel<<<NGRAPH, 256, 0, stream>>>(xpart, Wl, bl, out);
}